// Round 6
// baseline (182.331 us; speedup 1.0000x reference)
//
#include <hip/hip_runtime.h>
#include <hip/hip_bf16.h>

// out[b,e,d] = sum_l map[b,e,l]*doc[b,l,d] / lens[b,e];  B=8,E=512,L=4096,D=256 fp32.
//
// Barrier-free, LDS-free MFMA GEMM:
//  - A (map) fragments are k-contiguous in memory == MFMA A-layout -> direct
//    global->VGPR loads (4 waves/block redundant, L1 absorbs).
//  - B (doc) fragments: per-lane dword gathers (each instr = 2x128B segments).
//  - No __syncthreads -> no vmcnt(0) drains; compiler tracks per-load deps.
//  - 1024 blocks (e-tile 32 x full-D x SK8), <=128 VGPR -> 4 blocks/CU, 16 waves/CU.
#define B_N 8
#define E_N 512
#define L_N 4096
#define D_N 256

#define SK 8               // split-K
#define KC (L_N / SK)      // 512
#define STEPS (KC / 16)    // 32 MFMA K-steps per block

typedef __attribute__((ext_vector_type(8)))  short short8;
typedef __attribute__((ext_vector_type(16))) float f32x16;
typedef __attribute__((ext_vector_type(4)))  float f32x4;

union S8 { short8 s; unsigned int u[4]; };

// pack two fp32 -> packed bf16 pair (RNE); low 16 bits = lo
__device__ __forceinline__ unsigned int pk2(float lo, float hi) {
    __hip_bfloat162 h = __float22bfloat162_rn(make_float2(lo, hi));
    return *(unsigned int*)&h;
}

__global__ __launch_bounds__(256, 4)
void mp_gemm(const float* __restrict__ doc,   // [B,L,D]
             const float* __restrict__ map,   // [B,E,L]
             const float* __restrict__ lens,  // [B,E]
             float* __restrict__ out)         // [B,E,D] pre-zeroed, atomic accumulate
{
    const int e0  = blockIdx.x * 32;          // 16 e-tiles
    const int b   = blockIdx.y;
    const int kc0 = blockIdx.z * KC;

    const float* docB = doc + (size_t)b * L_N * D_N;
    const float* mapB = map + (size_t)b * E_N * L_N;
    float*       outB = out + (size_t)b * E_N * D_N;

    const int tid = threadIdx.x, lane = tid & 63, wave = tid >> 6;
    const int fm = lane & 31;    // m (A) / n (B) index
    const int fh = lane >> 5;    // k-half: k = fh*8 + j
    const int dw = wave * 64;    // wave's d-slice of the 256-wide tile

    // per-lane bases
    const float* aPtr = mapB + (size_t)(e0 + fm) * L_N + kc0 + fh * 8;       // k-contig
    const float* bPtr = docB + (size_t)(kc0 + fh * 8) * D_N + dw + fm;       // stride D_N

    f32x4 a[2][2];        // [buf][half] : 8 fp32 of A per step
    float bv[2][2][8];    // [buf][ni][j]: 8 strided fp32 per ni

    // preload step 0
    a[0][0] = *(const f32x4*)(aPtr);
    a[0][1] = *(const f32x4*)(aPtr + 4);
    #pragma unroll
    for (int ni = 0; ni < 2; ++ni)
        #pragma unroll
        for (int j = 0; j < 8; ++j)
            bv[0][ni][j] = bPtr[(size_t)j * D_N + ni * 32];

    f32x16 acc[2] = {};   // [ni] 32x32 tiles: rows e0..e0+31, cols dw+ni*32

    #pragma unroll 2
    for (int it = 0; it < STEPS; ++it) {
        const int cur = it & 1, nxt = cur ^ 1;

        // prefetch step it+1 (in flight across converts+MFMA of cur)
        if (it + 1 < STEPS) {
            const float* ap = aPtr + (size_t)(it + 1) * 16;
            a[nxt][0] = *(const f32x4*)(ap);
            a[nxt][1] = *(const f32x4*)(ap + 4);
            const float* bp = bPtr + (size_t)(it + 1) * 16 * D_N;
            #pragma unroll
            for (int ni = 0; ni < 2; ++ni)
                #pragma unroll
                for (int j = 0; j < 8; ++j)
                    bv[nxt][ni][j] = bp[(size_t)j * D_N + ni * 32];
        }

        // convert cur -> bf16 frags, 2 MFMA
        S8 af;
        af.u[0] = pk2(a[cur][0][0], a[cur][0][1]);
        af.u[1] = pk2(a[cur][0][2], a[cur][0][3]);
        af.u[2] = pk2(a[cur][1][0], a[cur][1][1]);
        af.u[3] = pk2(a[cur][1][2], a[cur][1][3]);
        #pragma unroll
        for (int ni = 0; ni < 2; ++ni) {
            S8 bf;
            #pragma unroll
            for (int p = 0; p < 4; ++p)
                bf.u[p] = pk2(bv[cur][ni][2 * p], bv[cur][ni][2 * p + 1]);
            acc[ni] = __builtin_amdgcn_mfma_f32_32x32x16_bf16(af.s, bf.s, acc[ni], 0, 0, 0);
        }
    }

    // epilogue: 32x32 C/D layout col=lane&31, row=(r&3)+8*(r>>2)+4*(lane>>5)
    #pragma unroll
    for (int r = 0; r < 16; ++r) {
        const int row = (r & 3) + 8 * (r >> 2) + 4 * fh;
        const float inv = 1.0f / lens[(size_t)b * E_N + e0 + row];  // L1-hit after first
        #pragma unroll
        for (int ni = 0; ni < 2; ++ni) {
            const int col = dw + ni * 32 + fm;
            atomicAdd(&outB[(size_t)(e0 + row) * D_N + col], acc[ni][r] * inv);
        }
    }
}

extern "C" void kernel_launch(void* const* d_in, const int* in_sizes, int n_in,
                              void* d_out, int out_size, void* d_ws, size_t ws_size,
                              hipStream_t stream) {
    const float* doc  = (const float*)d_in[0];
    const float* map  = (const float*)d_in[1];
    const float* lens = (const float*)d_in[2];
    float* out = (float*)d_out;

    // d_out poisoned 0xAA every call; split-K accumulates atomically.
    hipMemsetAsync(out, 0, (size_t)out_size * sizeof(float), stream);

    dim3 grid(E_N / 32, B_N, SK);   // 16 x 8 x 8 = 1024 blocks -> 4/CU
    mp_gemm<<<grid, 256, 0, stream>>>(doc, map, lens, out);
}

// Round 7
// 158.629 us; speedup vs baseline: 1.1494x; 1.1494x over previous
//
#include <hip/hip_runtime.h>

// out[b,e,d] = sum_l map[b,e,l]*doc[b,l,d] / lens[b,e];  B=8,E=512,L=4096,D=256 fp32.
//
// R7 = R2's proven 64x64-tile LDS kernel (fastest so far, 61us) with:
//  - SK=8 -> 2048 blocks = exactly 8 blocks/CU, whole grid co-resident
//    (__launch_bounds__(256,8); 48 VGPR / 18.9KB LDS fits 8/CU).
//  - XCD-aware 1D decode: all 32 (e,d) tiles of one (b,sk) pair land on ONE
//    XCD (id&7 round-robin heuristic) -> shared doc slice (512KB) + map tiles
//    served from that XCD's 4MB L2: FETCH -> ~ideal, doc latency HBM -> L2.
#define B_N 8
#define E_N 512
#define L_N 4096
#define D_N 256

#define SK 8                 // split-K chunks
#define KC (L_N / SK)        // 512
#define ITERS (KC / 64)      // 8

typedef __attribute__((ext_vector_type(8))) short short8;
typedef __attribute__((ext_vector_type(4))) short short4v;
typedef __attribute__((ext_vector_type(4))) float f32x4;

__device__ __forceinline__ unsigned short f2bf(float f) {
    unsigned u = __float_as_uint(f);
    u += 0x7fffu + ((u >> 16) & 1u);
    return (unsigned short)(u >> 16);
}

#define LDT 72   // LDS leading dim (shorts): 16B-aligned b128 frag reads

__global__ __launch_bounds__(256, 8)
void mp_gemm(const float* __restrict__ doc,   // [B,L,D]
             const float* __restrict__ map,   // [B,E,L]
             const float* __restrict__ lens,  // [B,E]
             float* __restrict__ out)         // [B,E,D] pre-zeroed, atomic accumulate
{
    __shared__ unsigned short As[64 * LDT];   // As[m][k] bf16
    __shared__ unsigned short Bs[64 * LDT];   // Bs[n][k] bf16 (transposed in regs)
    __shared__ float invLen[64];

    // ---- XCD-aware decode: same (b,sk) -> same XCD (id&7), all 32 tiles of it ----
    const int id   = blockIdx.x;
    const int xcd  = id & 7;
    const int loc  = id >> 3;          // [0,256) within XCD
    const int tile = loc & 31;         // 8 e-tiles x 4 d-tiles
    const int grp  = loc >> 5;         // [0,8) pair-group within XCD
    const int p    = grp * 8 + xcd;    // (b,sk) pair [0,64)
    const int b    = p >> 3;
    const int kc0  = (p & 7) * KC;
    const int e0   = (tile >> 2) * 64;
    const int d0   = (tile & 3) * 64;

    const float* docB = doc + (size_t)b * L_N * D_N;
    const float* mapB = map + (size_t)b * E_N * L_N;
    float*       outB = out + (size_t)b * E_N * D_N;

    const int tid = threadIdx.x, lane = tid & 63, wave = tid >> 6;
    if (tid < 64) invLen[tid] = 1.0f / lens[(size_t)b * E_N + e0 + tid];

    // A staging: row = (t>>4)+16r, 16B col chunk = t&15
    const int aRow0 = tid >> 4;
    const int aCol4 = tid & 15;
    // B staging: 4x4 micro-block transpose in regs; nb = d-block (coalesced), kb = k-block
    const int nb = tid & 15;
    const int kb = tid >> 4;

    f32x4 ar[4], br[4];
    {
        #pragma unroll
        for (int r = 0; r < 4; ++r)
            ar[r] = *(const f32x4*)(mapB + (size_t)(e0 + aRow0 + r * 16) * L_N + kc0 + aCol4 * 4);
        #pragma unroll
        for (int i = 0; i < 4; ++i)
            br[i] = *(const f32x4*)(docB + (size_t)(kc0 + kb * 4 + i) * D_N + d0 + nb * 4);
    }

    const int wm = wave >> 1, wn = wave & 1, fm = lane & 15, q = lane >> 4;
    f32x4 acc[2][2] = {};

    for (int it = 0; it < ITERS; ++it) {
        if (it) __syncthreads();

        #pragma unroll
        for (int r = 0; r < 4; ++r) {
            short4v w;
            w[0] = (short)f2bf(ar[r][0]); w[1] = (short)f2bf(ar[r][1]);
            w[2] = (short)f2bf(ar[r][2]); w[3] = (short)f2bf(ar[r][3]);
            *(short4v*)&As[(aRow0 + r * 16) * LDT + aCol4 * 4] = w;
        }
        #pragma unroll
        for (int j = 0; j < 4; ++j) {
            short4v w;
            w[0] = (short)f2bf(br[0][j]); w[1] = (short)f2bf(br[1][j]);
            w[2] = (short)f2bf(br[2][j]); w[3] = (short)f2bf(br[3][j]);
            *(short4v*)&Bs[(nb * 4 + j) * LDT + kb * 4] = w;
        }
        __syncthreads();

        // prefetch next tile into regs (in flight across MFMA phase)
        if (it + 1 < ITERS) {
            const int k0 = kc0 + (it + 1) * 64;
            #pragma unroll
            for (int r = 0; r < 4; ++r)
                ar[r] = *(const f32x4*)(mapB + (size_t)(e0 + aRow0 + r * 16) * L_N + k0 + aCol4 * 4);
            #pragma unroll
            for (int i = 0; i < 4; ++i)
                br[i] = *(const f32x4*)(docB + (size_t)(k0 + kb * 4 + i) * D_N + d0 + nb * 4);
        }

        #pragma unroll
        for (int kk = 0; kk < 2; ++kk) {
            short8 af[2], bf[2];
            #pragma unroll
            for (int mi = 0; mi < 2; ++mi)
                af[mi] = *(const short8*)&As[(wm * 32 + mi * 16 + fm) * LDT + kk * 32 + q * 8];
            #pragma unroll
            for (int ni = 0; ni < 2; ++ni)
                bf[ni] = *(const short8*)&Bs[(wn * 32 + ni * 16 + fm) * LDT + kk * 32 + q * 8];
            #pragma unroll
            for (int mi = 0; mi < 2; ++mi)
                #pragma unroll
                for (int ni = 0; ni < 2; ++ni)
                    acc[mi][ni] = __builtin_amdgcn_mfma_f32_16x16x32_bf16(
                        af[mi], bf[ni], acc[mi][ni], 0, 0, 0);
        }
    }

    // epilogue: 16x16 C/D layout col=lane&15, row=(lane>>4)*4+i; scale + atomic add
    #pragma unroll
    for (int mi = 0; mi < 2; ++mi) {
        const int rLoc = wm * 32 + mi * 16 + q * 4;
        #pragma unroll
        for (int ni = 0; ni < 2; ++ni) {
            const int c = d0 + wn * 32 + ni * 16 + fm;
            #pragma unroll
            for (int i = 0; i < 4; ++i) {
                const int rr = rLoc + i;
                atomicAdd(&outB[(size_t)(e0 + rr) * D_N + c], acc[mi][ni][i] * invLen[rr]);
            }
        }
    }
}

extern "C" void kernel_launch(void* const* d_in, const int* in_sizes, int n_in,
                              void* d_out, int out_size, void* d_ws, size_t ws_size,
                              hipStream_t stream) {
    const float* doc  = (const float*)d_in[0];
    const float* map  = (const float*)d_in[1];
    const float* lens = (const float*)d_in[2];
    float* out = (float*)d_out;

    // d_out poisoned 0xAA every call; split-K accumulates atomically.
    hipMemsetAsync(out, 0, (size_t)out_size * sizeof(float), stream);

    // 2048 blocks = 8 e-tiles x 4 d-tiles x 8 b x 8 sk, 1D for XCD decode.
    mp_gemm<<<dim3(2048), 256, 0, stream>>>(doc, map, lens, out);
}